// Round 12
// baseline (864.740 us; speedup 1.0000x reference)
//
#include <hip/hip_runtime.h>

// ---------------------------------------------------------------------------
// MagNet link prediction forward, f32 (16-bit quant fails: ReLU mask flips).
// Gather CSR, telescoped Chebyshev: out = x@(W0-W2)+b + prop(g1+2*prop(g2)).
// Round 12: 2-LEVEL CSR (dst x src-chunk, C=16) + chunk-major gathers.
// All resident blocks sweep src-chunks in the same order -> the 3.2MB (gC) /
// 1.6MB (gU) source window stays L2-resident, attacking the 49% L2 miss rate
// that pins sparse passes at 3.65 TB/s beyond-L2. Waves own 8 (gC) / 4 (gU)
// destinations so per-chunk phases are big enough to stay aligned.
// ---------------------------------------------------------------------------

#define CHK 16

__device__ __forceinline__ float4 ld4(const float* __restrict__ p) {
  return *reinterpret_cast<const float4*>(p);
}
__device__ __forceinline__ float2 ld2(const float* __restrict__ p) {
  return *reinterpret_cast<const float2*>(p);
}

// ---- fused: [deg + (dst,chunk) count prefix] + 6-stream GEMM (layer 1) ------
template <int K>
__global__ __launch_bounds__(256) void k_gemm_deg(
    const int* __restrict__ u, const int* __restrict__ v,
    const float* __restrict__ w, float* __restrict__ deg,
    int* __restrict__ cnt2, int E, int epb, int N,
    const float* __restrict__ Ar, const float* __restrict__ Ai,
    const float* __restrict__ W, const float* __restrict__ bias,
    float* __restrict__ P1, float* __restrict__ P2,
    float* __restrict__ Hr, float* __restrict__ Hi, int M) {
  __shared__ float Asr[32][36];
  __shared__ float Asi[32][36];
  __shared__ float Ws1[32][64];
  __shared__ float Ws2[32][64];
  __shared__ float Wsm[32][64];
  const int t = threadIdx.x;
  {  // --- prefix: fire-and-forget atomics, no dependent reads ---
    int e0 = blockIdx.x * epb;
    int e1 = min(e0 + epb, E);
    for (int e = e0 + t; e < e1; e += 256) {
      int a = u[e], b = v[e];
      float hw = 0.5f * w[e];
      unsafeAtomicAdd(&deg[a], hw);
      unsafeAtomicAdd(&deg[b], hw);
      int ca = (a * CHK) / N, cb = (b * CHK) / N;
      atomicAdd(&cnt2[b * CHK + ca], 1);  // fwd a->b lives in (b, chunk(a))
      atomicAdd(&cnt2[a * CHK + cb], 1);  // rev b->a lives in (a, chunk(b))
    }
  }
  // --- GEMM: BM=32, BK=32, A+W in LDS ---
  const int r0 = blockIdx.x * 32;
  const int tc = t & 15, tr = t >> 4;
  const float* W0 = W;
  const float* W1 = W + (size_t)K * 64;
  const float* W2 = W + (size_t)2 * K * 64;
  float a1r[2][4] = {}, a1i[2][4] = {}, a2r[2][4] = {}, a2i[2][4] = {};
  float amr[2][4] = {}, ami[2][4] = {};
  for (int k0 = 0; k0 < K; k0 += 32) {
    {
      int row = t >> 3, c4 = t & 7;
      int gr = r0 + row;
      float4 fr = make_float4(0.f, 0.f, 0.f, 0.f), fi = fr;
      if (gr < M) {
        fr = ld4(&Ar[(size_t)gr * K + k0 + c4 * 4]);
        fi = ld4(&Ai[(size_t)gr * K + k0 + c4 * 4]);
      }
      *reinterpret_cast<float4*>(&Asr[row][c4 * 4]) = fr;
      *reinterpret_cast<float4*>(&Asi[row][c4 * 4]) = fi;
    }
    for (int li = t; li < 512; li += 256) {
      int row = li >> 4, c4 = li & 15;
      size_t woff = (size_t)(k0 + row) * 64 + c4 * 4;
      float4 w1 = ld4(&W1[woff]);
      float4 w2 = ld4(&W2[woff]);
      float4 w0 = ld4(&W0[woff]);
      *reinterpret_cast<float4*>(&Ws1[row][c4 * 4]) = w1;
      *reinterpret_cast<float4*>(&Ws2[row][c4 * 4]) = w2;
      *reinterpret_cast<float4*>(&Wsm[row][c4 * 4]) =
          make_float4(w0.x - w2.x, w0.y - w2.y, w0.z - w2.z, w0.w - w2.w);
    }
    __syncthreads();
#pragma unroll 4
    for (int k = 0; k < 32; ++k) {
      float4 b1 = *reinterpret_cast<const float4*>(&Ws1[k][tc * 4]);
      float4 b2 = *reinterpret_cast<const float4*>(&Ws2[k][tc * 4]);
      float4 bm = *reinterpret_cast<const float4*>(&Wsm[k][tc * 4]);
#pragma unroll
      for (int i = 0; i < 2; ++i) {
        float ar = Asr[tr * 2 + i][k], ai = Asi[tr * 2 + i][k];
        a1r[i][0] += ar * b1.x; a1r[i][1] += ar * b1.y; a1r[i][2] += ar * b1.z; a1r[i][3] += ar * b1.w;
        a1i[i][0] += ai * b1.x; a1i[i][1] += ai * b1.y; a1i[i][2] += ai * b1.z; a1i[i][3] += ai * b1.w;
        a2r[i][0] += ar * b2.x; a2r[i][1] += ar * b2.y; a2r[i][2] += ar * b2.z; a2r[i][3] += ar * b2.w;
        a2i[i][0] += ai * b2.x; a2i[i][1] += ai * b2.y; a2i[i][2] += ai * b2.z; a2i[i][3] += ai * b2.w;
        amr[i][0] += ar * bm.x; amr[i][1] += ar * bm.y; amr[i][2] += ar * bm.z; amr[i][3] += ar * bm.w;
        ami[i][0] += ai * bm.x; ami[i][1] += ai * bm.y; ami[i][2] += ai * bm.z; ami[i][3] += ai * bm.w;
      }
    }
    __syncthreads();
  }
  float b0 = bias[tc * 4 + 0], bb1 = bias[tc * 4 + 1];
  float b2v = bias[tc * 4 + 2], b3 = bias[tc * 4 + 3];
#pragma unroll
  for (int i = 0; i < 2; ++i) {
    int gr = r0 + tr * 2 + i;
    if (gr >= M) continue;
    size_t pb = (size_t)gr * 128 + tc * 8;
    *reinterpret_cast<float4*>(&P1[pb]) =
        make_float4(a1r[i][0], a1i[i][0], a1r[i][1], a1i[i][1]);
    *reinterpret_cast<float4*>(&P1[pb + 4]) =
        make_float4(a1r[i][2], a1i[i][2], a1r[i][3], a1i[i][3]);
    *reinterpret_cast<float4*>(&P2[pb]) =
        make_float4(a2r[i][0], a2i[i][0], a2r[i][1], a2i[i][1]);
    *reinterpret_cast<float4*>(&P2[pb + 4]) =
        make_float4(a2r[i][2], a2i[i][2], a2r[i][3], a2i[i][3]);
    size_t hb = (size_t)gr * 64 + tc * 4;
    *reinterpret_cast<float4*>(&Hr[hb]) =
        make_float4(amr[i][0] - ami[i][0] + b0, amr[i][1] - ami[i][1] + bb1,
                    amr[i][2] - ami[i][2] + b2v, amr[i][3] - ami[i][3] + b3);
    *reinterpret_cast<float4*>(&Hi[hb]) =
        make_float4(amr[i][0] + ami[i][0] + b0, amr[i][1] + ami[i][1] + bb1,
                    amr[i][2] + ami[i][2] + b2v, amr[i][3] + ami[i][3] + b3);
  }
}

// ---- standalone GEMM (layer 2) ----------------------------------------------
template <int K>
__global__ __launch_bounds__(256) void k_gemmF(
    const float* __restrict__ Ar, const float* __restrict__ Ai,
    const float* __restrict__ W, const float* __restrict__ bias,
    float* __restrict__ P1, float* __restrict__ P2,
    float* __restrict__ Hr, float* __restrict__ Hi, int M) {
  __shared__ float Asr[32][36];
  __shared__ float Asi[32][36];
  __shared__ float Ws1[32][64];
  __shared__ float Ws2[32][64];
  __shared__ float Wsm[32][64];
  const int t = threadIdx.x;
  const int r0 = blockIdx.x * 32;
  const int tc = t & 15, tr = t >> 4;
  const float* W0 = W;
  const float* W1 = W + (size_t)K * 64;
  const float* W2 = W + (size_t)2 * K * 64;
  float a1r[2][4] = {}, a1i[2][4] = {}, a2r[2][4] = {}, a2i[2][4] = {};
  float amr[2][4] = {}, ami[2][4] = {};
  for (int k0 = 0; k0 < K; k0 += 32) {
    {
      int row = t >> 3, c4 = t & 7;
      int gr = r0 + row;
      float4 fr = make_float4(0.f, 0.f, 0.f, 0.f), fi = fr;
      if (gr < M) {
        fr = ld4(&Ar[(size_t)gr * K + k0 + c4 * 4]);
        fi = ld4(&Ai[(size_t)gr * K + k0 + c4 * 4]);
      }
      *reinterpret_cast<float4*>(&Asr[row][c4 * 4]) = fr;
      *reinterpret_cast<float4*>(&Asi[row][c4 * 4]) = fi;
    }
    for (int li = t; li < 512; li += 256) {
      int row = li >> 4, c4 = li & 15;
      size_t woff = (size_t)(k0 + row) * 64 + c4 * 4;
      float4 w1 = ld4(&W1[woff]);
      float4 w2 = ld4(&W2[woff]);
      float4 w0 = ld4(&W0[woff]);
      *reinterpret_cast<float4*>(&Ws1[row][c4 * 4]) = w1;
      *reinterpret_cast<float4*>(&Ws2[row][c4 * 4]) = w2;
      *reinterpret_cast<float4*>(&Wsm[row][c4 * 4]) =
          make_float4(w0.x - w2.x, w0.y - w2.y, w0.z - w2.z, w0.w - w2.w);
    }
    __syncthreads();
#pragma unroll 4
    for (int k = 0; k < 32; ++k) {
      float4 b1 = *reinterpret_cast<const float4*>(&Ws1[k][tc * 4]);
      float4 b2 = *reinterpret_cast<const float4*>(&Ws2[k][tc * 4]);
      float4 bm = *reinterpret_cast<const float4*>(&Wsm[k][tc * 4]);
#pragma unroll
      for (int i = 0; i < 2; ++i) {
        float ar = Asr[tr * 2 + i][k], ai = Asi[tr * 2 + i][k];
        a1r[i][0] += ar * b1.x; a1r[i][1] += ar * b1.y; a1r[i][2] += ar * b1.z; a1r[i][3] += ar * b1.w;
        a1i[i][0] += ai * b1.x; a1i[i][1] += ai * b1.y; a1i[i][2] += ai * b1.z; a1i[i][3] += ai * b1.w;
        a2r[i][0] += ar * b2.x; a2r[i][1] += ar * b2.y; a2r[i][2] += ar * b2.z; a2r[i][3] += ar * b2.w;
        a2i[i][0] += ai * b2.x; a2i[i][1] += ai * b2.y; a2i[i][2] += ai * b2.z; a2i[i][3] += ai * b2.w;
        amr[i][0] += ar * bm.x; amr[i][1] += ar * bm.y; amr[i][2] += ar * bm.z; amr[i][3] += ar * bm.w;
        ami[i][0] += ai * bm.x; ami[i][1] += ai * bm.y; ami[i][2] += ai * bm.z; ami[i][3] += ai * bm.w;
      }
    }
    __syncthreads();
  }
  float b0 = bias[tc * 4 + 0], bb1 = bias[tc * 4 + 1];
  float b2v = bias[tc * 4 + 2], b3 = bias[tc * 4 + 3];
#pragma unroll
  for (int i = 0; i < 2; ++i) {
    int gr = r0 + tr * 2 + i;
    if (gr >= M) continue;
    size_t pb = (size_t)gr * 128 + tc * 8;
    *reinterpret_cast<float4*>(&P1[pb]) =
        make_float4(a1r[i][0], a1i[i][0], a1r[i][1], a1i[i][1]);
    *reinterpret_cast<float4*>(&P1[pb + 4]) =
        make_float4(a1r[i][2], a1i[i][2], a1r[i][3], a1i[i][3]);
    *reinterpret_cast<float4*>(&P2[pb]) =
        make_float4(a2r[i][0], a2i[i][0], a2r[i][1], a2i[i][1]);
    *reinterpret_cast<float4*>(&P2[pb + 4]) =
        make_float4(a2r[i][2], a2i[i][2], a2r[i][3], a2i[i][3]);
    size_t hb = (size_t)gr * 64 + tc * 4;
    *reinterpret_cast<float4*>(&Hr[hb]) =
        make_float4(amr[i][0] - ami[i][0] + b0, amr[i][1] - ami[i][1] + bb1,
                    amr[i][2] - ami[i][2] + b2v, amr[i][3] - ami[i][3] + b3);
    *reinterpret_cast<float4*>(&Hi[hb]) =
        make_float4(amr[i][0] + ami[i][0] + b0, amr[i][1] + ami[i][1] + bb1,
                    amr[i][2] + ami[i][2] + b2v, amr[i][3] + ami[i][3] + b3);
  }
}

// ---- exclusive scan of cnt2[NC] -> rp2 --------------------------------------
__global__ __launch_bounds__(256) void k_scan1(
    const int* __restrict__ cnt2, int* __restrict__ rp2,
    int* __restrict__ bsum, int NC) {
  __shared__ int sh[256];
  int t = threadIdx.x;
  int base = blockIdx.x * 1024 + t * 4;
  int c0 = (base + 0 < NC) ? cnt2[base + 0] : 0;
  int c1 = (base + 1 < NC) ? cnt2[base + 1] : 0;
  int c2 = (base + 2 < NC) ? cnt2[base + 2] : 0;
  int c3 = (base + 3 < NC) ? cnt2[base + 3] : 0;
  int s = c0 + c1 + c2 + c3;
  sh[t] = s;
  __syncthreads();
  for (int o = 1; o < 256; o <<= 1) {
    int y = (t >= o) ? sh[t - o] : 0;
    __syncthreads();
    if (t >= o) sh[t] += y;
    __syncthreads();
  }
  int excl = sh[t] - s;
  if (base + 0 < NC) rp2[base + 0] = excl;
  if (base + 1 < NC) rp2[base + 1] = excl + c0;
  if (base + 2 < NC) rp2[base + 2] = excl + c0 + c1;
  if (base + 3 < NC) rp2[base + 3] = excl + c0 + c1 + c2;
  if (t == 255) bsum[blockIdx.x] = sh[255];
}

// ---- scan3: add block-sum prefix, copy to nxt2 ------------------------------
__global__ void k_scan3(int* __restrict__ rp2, int* __restrict__ nxt2,
                        const int* __restrict__ bsum, int NC, int twoE) {
  int i = blockIdx.x * 256 + threadIdx.x;
  if (i > NC) return;
  if (i == NC) { rp2[NC] = twoE; return; }
  int b = i >> 10;
  int pre = 0;
  for (int j = 0; j < b; ++j) pre += bsum[j];  // wave-uniform loop
  int val = rp2[i] + pre;
  rp2[i] = val;
  nxt2[i] = val;
}

// ---- scatter into (dst, src-chunk) buckets ----------------------------------
__global__ void k_scatter(const int* __restrict__ u, const int* __restrict__ v,
                          const float* __restrict__ w,
                          const float* __restrict__ deg,
                          int* __restrict__ nxt2, int* __restrict__ src,
                          float2* __restrict__ cf, int E, int N) {
  int e = blockIdx.x * 256 + threadIdx.x;
  if (e >= E) return;
  int a = u[e], b = v[e];
  float we = w[e];
  float da = deg[a], db = deg[b];
  float ia = da > 0.f ? rsqrtf(da) : 0.f;
  float ib = db > 0.f ? rsqrtf(db) : 0.f;
  float norm = ia * (0.5f * we) * ib;
  float th = 1.57079632679489662f * we;  // 2*pi*q*w, q=0.25
  float sn, cs;
  sincosf(th, &sn, &cs);
  float cr = -norm * cs, ci = -norm * sn;
  int ca = (a * CHK) / N, cb = (b * CHK) / N;
  int p1 = atomicAdd(&nxt2[b * CHK + ca], 1);  // fwd a->b, coeff (cr, ci)
  src[p1] = a;
  cf[p1] = make_float2(cr, ci);
  int p2 = atomicAdd(&nxt2[a * CHK + cb], 1);  // rev b->a, coeff (cr, -ci)
  src[p2] = b;
  cf[p2] = make_float2(cr, -ci);
}

// ---- gU: chunk-major, 4 dests/wave; Z = [P1+2*(u0,u1) | P1+2*(u2,u3)] -------
__global__ __launch_bounds__(256) void k_gU(
    const int* __restrict__ src, const float2* __restrict__ cf,
    const int* __restrict__ rp2, const float* __restrict__ P2,
    const float* __restrict__ P1, float* __restrict__ Z, int N) {
  int wave = threadIdx.x >> 6;
  int d0 = (blockIdx.x * 4 + wave) * 4;
  int lane = threadIdx.x & 63;
  int g = lane >> 5, lg = lane & 31;
  float4 a01[4] = {}, a23[4] = {};
  for (int c = 0; c < CHK; ++c) {
#pragma unroll
    for (int j = 0; j < 4; ++j) {
      int d = d0 + j;
      if (d >= N) continue;
      int base = d * CHK + c;
      int k0 = rp2[base], k1 = rp2[base + 1];
      for (int k = k0 + g; k < k1; k += 2) {
        int s = src[k];
        float2 cc = cf[k];
        float4 vv = ld4(P2 + (size_t)s * 128 + lg * 4);
        a01[j].x += cc.x * vv.x; a01[j].y += cc.y * vv.y;
        a01[j].z += cc.x * vv.z; a01[j].w += cc.y * vv.w;
        a23[j].x += cc.y * vv.x; a23[j].y += cc.x * vv.y;
        a23[j].z += cc.y * vv.z; a23[j].w += cc.x * vv.w;
      }
    }
  }
#pragma unroll
  for (int j = 0; j < 4; ++j) {
    int d = d0 + j;
    if (d >= N) continue;
    a01[j].x += __shfl_xor(a01[j].x, 32); a01[j].y += __shfl_xor(a01[j].y, 32);
    a01[j].z += __shfl_xor(a01[j].z, 32); a01[j].w += __shfl_xor(a01[j].w, 32);
    a23[j].x += __shfl_xor(a23[j].x, 32); a23[j].y += __shfl_xor(a23[j].y, 32);
    a23[j].z += __shfl_xor(a23[j].z, 32); a23[j].w += __shfl_xor(a23[j].w, 32);
    float4 p = ld4(P1 + (size_t)d * 128 + lg * 4);
    size_t zb = (size_t)d * 256 + lg * 4;
    if (g == 0)
      *reinterpret_cast<float4*>(&Z[zb]) =
          make_float4(p.x + 2.f * a01[j].x, p.y + 2.f * a01[j].y,
                      p.z + 2.f * a01[j].z, p.w + 2.f * a01[j].w);
    else
      *reinterpret_cast<float4*>(&Z[zb + 128]) =
          make_float4(p.x + 2.f * a23[j].x, p.y + 2.f * a23[j].y,
                      p.z + 2.f * a23[j].z, p.w + 2.f * a23[j].w);
  }
}

// ---- gC: chunk-major, 8 dests/wave; H += prop(Z); complex ReLU --------------
__global__ __launch_bounds__(256) void k_gC(
    const int* __restrict__ src, const float2* __restrict__ cf,
    const int* __restrict__ rp2, const float* __restrict__ Z,
    float* __restrict__ Hr, float* __restrict__ Hi, int N) {
  int wave = threadIdx.x >> 6;
  int d0 = (blockIdx.x * 4 + wave) * 8;
  int lane = threadIdx.x & 63;
  int g = lane >> 5, lg = lane & 31;
  float2 ahr[8] = {}, ahi[8] = {};
  for (int c = 0; c < CHK; ++c) {
#pragma unroll
    for (int j = 0; j < 8; ++j) {
      int d = d0 + j;
      if (d >= N) continue;
      int base = d * CHK + c;
      int k0 = rp2[base], k1 = rp2[base + 1];
      for (int k = k0 + g; k < k1; k += 2) {
        int s = src[k];
        float2 cc = cf[k];
        const float* row = Z + (size_t)s * 256 + lg * 4;
        float4 z1 = ld4(row);
        float4 z2 = ld4(row + 128);
        ahr[j].x += cc.x * z1.x - cc.y * z1.y;
        ahr[j].y += cc.x * z1.z - cc.y * z1.w;
        ahi[j].x += cc.y * z2.x + cc.x * z2.y;
        ahi[j].y += cc.y * z2.z + cc.x * z2.w;
      }
    }
  }
#pragma unroll
  for (int j = 0; j < 8; ++j) {
    int d = d0 + j;
    if (d >= N) continue;
    ahr[j].x += __shfl_xor(ahr[j].x, 32);
    ahr[j].y += __shfl_xor(ahr[j].y, 32);
    ahi[j].x += __shfl_xor(ahi[j].x, 32);
    ahi[j].y += __shfl_xor(ahi[j].y, 32);
    if (g == 0) {
      size_t hb = (size_t)d * 64 + lg * 2;
      float2 hr = ld2(&Hr[hb]);
      float2 hi = ld2(&Hi[hb]);
      hr.x += ahr[j].x; hr.y += ahr[j].y;
      hi.x += ahi[j].x; hi.y += ahi[j].y;
      if (hr.x < 0.f) { hr.x = 0.f; hi.x = 0.f; }
      if (hr.y < 0.f) { hr.y = 0.f; hi.y = 0.f; }
      *reinterpret_cast<float2*>(&Hr[hb]) = hr;
      *reinterpret_cast<float2*>(&Hi[hb]) = hi;
    }
  }
}

// ---- query gather + linear + log_softmax ------------------------------------
__global__ __launch_bounds__(256) void k_query(
    const int* __restrict__ qe, const float* __restrict__ xr,
    const float* __restrict__ xi, const float* __restrict__ Wlin,
    const float* __restrict__ blin, float* __restrict__ out, int Q) {
  int q = blockIdx.x * 4 + (threadIdx.x >> 6);
  if (q >= Q) return;
  int lane = threadIdx.x & 63;
  int q0 = qe[2 * q], q1 = qe[2 * q + 1];
  float x0 = xr[(size_t)q0 * 64 + lane];
  float x1 = xr[(size_t)q1 * 64 + lane];
  float x2 = xi[(size_t)q0 * 64 + lane];
  float x3 = xi[(size_t)q1 * 64 + lane];
  float l0 = x0 * Wlin[lane] + x1 * Wlin[64 + lane] + x2 * Wlin[128 + lane] + x3 * Wlin[192 + lane];
  float l1 = x0 * Wlin[256 + lane] + x1 * Wlin[320 + lane] + x2 * Wlin[384 + lane] + x3 * Wlin[448 + lane];
#pragma unroll
  for (int o = 32; o > 0; o >>= 1) {
    l0 += __shfl_xor(l0, o);
    l1 += __shfl_xor(l1, o);
  }
  if (lane == 0) {
    l0 += blin[0];
    l1 += blin[1];
    float m = fmaxf(l0, l1);
    float lse = m + logf(expf(l0 - m) + expf(l1 - m));
    out[2 * q + 0] = l0 - lse;
    out[2 * q + 1] = l1 - lse;
  }
}

extern "C" void kernel_launch(void* const* d_in, const int* in_sizes, int n_in,
                              void* d_out, int out_size, void* d_ws, size_t ws_size,
                              hipStream_t stream) {
  const float* real = (const float*)d_in[0];
  const float* imag = (const float*)d_in[1];
  const int* ei     = (const int*)d_in[2];
  const int* qe     = (const int*)d_in[3];
  const float* ew   = (const float*)d_in[4];
  const float* W1   = (const float*)d_in[5];
  const float* b1   = (const float*)d_in[6];
  const float* W2   = (const float*)d_in[7];
  const float* b2   = (const float*)d_in[8];
  const float* Wlin = (const float*)d_in[9];
  const float* blin = (const float*)d_in[10];

  const int N = in_sizes[0] / 128;
  const int E = in_sizes[4];
  const int Q = in_sizes[3] / 2;
  const int* u = ei;
  const int* v = ei + E;
  const int NC = N * CHK;

  float* ws = (float*)d_ws;
  size_t off = 0;
  auto alloc = [&](size_t n) { float* p = ws + off; off += n; return p; };
  const size_t N64 = (size_t)N * 64;
  const size_t N128 = (size_t)N * 128;
  const size_t N256 = (size_t)N * 256;

  float2* cf = (float2*)alloc((size_t)2 * E * 2);                 // 8B-aligned
  int* src  = (int*)alloc((size_t)2 * E);
  float* P1  = alloc(N128);
  float* P2  = alloc(N128);
  float* Z   = alloc(N256);
  float* HAr = alloc(N64);
  float* HAi = alloc(N64);
  float* HBr = alloc(N64);
  float* HBi = alloc(N64);
  float* deg = alloc(N);
  int* cnt2 = (int*)alloc(NC);
  int* rp2  = (int*)alloc(NC + 1);
  int* nxt2 = (int*)alloc(NC);
  int* bsum = (int*)alloc(1024);
  (void)ws_size; (void)n_in; (void)out_size;

  const int eb = (E + 255) / 256;
  const int mb = (N + 31) / 32;
  const int NB = (NC + 1023) / 1024;
  const int gbU = (N + 15) / 16;
  const int gbC = (N + 31) / 32;
  const int epb = (E + mb - 1) / mb;

  // --- dispatch 1: layer-1 GEMM with deg/count prefix slices ---
  hipMemsetAsync(deg, 0, (size_t)N * 4, stream);
  hipMemsetAsync(cnt2, 0, (size_t)NC * 4, stream);
  k_gemm_deg<128><<<mb, 256, 0, stream>>>(
      u, v, ew, deg, cnt2, E, epb, N, real, imag, W1, b1, P1, P2, HAr, HAi, N);
  // --- 2-level CSR ---
  k_scan1<<<NB, 256, 0, stream>>>(cnt2, rp2, bsum, NC);
  k_scan3<<<(NC + 256) / 256, 256, 0, stream>>>(rp2, nxt2, bsum, NC, 2 * E);
  k_scatter<<<eb, 256, 0, stream>>>(u, v, ew, deg, nxt2, src, cf, E, N);

  // --- layer 1 sparse ---
  k_gU<<<gbU, 256, 0, stream>>>(src, cf, rp2, P2, P1, Z, N);
  k_gC<<<gbC, 256, 0, stream>>>(src, cf, rp2, Z, HAr, HAi, N);

  // --- layer 2 ---
  k_gemmF<64><<<mb, 256, 0, stream>>>(HAr, HAi, W2, b2, P1, P2, HBr, HBi, N);
  k_gU<<<gbU, 256, 0, stream>>>(src, cf, rp2, P2, P1, Z, N);
  k_gC<<<gbC, 256, 0, stream>>>(src, cf, rp2, Z, HBr, HBi, N);

  // --- queries ---
  k_query<<<(Q + 3) / 4, 256, 0, stream>>>(qe, HBr, HBi, Wlin, blin, (float*)d_out, Q);
}

// Round 13
// 805.618 us; speedup vs baseline: 1.0734x; 1.0734x over previous
//
#include <hip/hip_runtime.h>

// ---------------------------------------------------------------------------
// MagNet link prediction forward, f32 (16-bit quant fails: ReLU mask flips).
// Gather CSR, telescoped Chebyshev: out = x@(W0-W2)+b + prop(g1+2*prop(g2)).
// Round 13: 2-level CSR (dst x src-chunk, C=16) kept — round 12 proved the
// chunk-major sweep cuts gC FETCH 485->364MB — but with the overhead removed:
//  * prefix back to 2 u64 atomics/edge: dc2[bucket] += (1<<32)|fx24(0.5w);
//    deg[node] = sum of its 16 bucket lows, extracted inside scan1's sweep.
//  * gathers are FULL-WAVE-PER-EDGE (no lane-group split, no shuffle
//    reductions): gU lane=feature (8B), gC lane-halves own z1/z2 (16B);
//    4 dests/wave; 17 descriptor bounds per dest fetched as one vector load
//    and distributed via __shfl. ReLU hr<->hi exchange = one shfl_xor(32).
// ---------------------------------------------------------------------------

#define CHK 16

__device__ __forceinline__ float4 ld4(const float* __restrict__ p) {
  return *reinterpret_cast<const float4*>(p);
}
__device__ __forceinline__ float2 ld2(const float* __restrict__ p) {
  return *reinterpret_cast<const float2*>(p);
}

// ---- fused: [bucket count+deg u64 atomics prefix] + 6-stream GEMM (L1) ------
template <int K>
__global__ __launch_bounds__(256) void k_gemm_deg(
    const int* __restrict__ u, const int* __restrict__ v,
    const float* __restrict__ w, unsigned long long* __restrict__ dc2,
    int E, int epb, int N,
    const float* __restrict__ Ar, const float* __restrict__ Ai,
    const float* __restrict__ W, const float* __restrict__ bias,
    float* __restrict__ P1, float* __restrict__ P2,
    float* __restrict__ Hr, float* __restrict__ Hi, int M) {
  __shared__ float Asr[32][36];
  __shared__ float Asi[32][36];
  __shared__ float Ws1[32][64];
  __shared__ float Ws2[32][64];
  __shared__ float Wsm[32][64];
  const int t = threadIdx.x;
  {  // --- prefix: fire-and-forget packed atomics ---
    int e0 = blockIdx.x * epb;
    int e1 = min(e0 + epb, E);
    for (int e = e0 + t; e < e1; e += 256) {
      int a = u[e], b = v[e];
      unsigned fx = __float2uint_rn(0.5f * w[e] * 16777216.f);
      unsigned long long pk = (1ULL << 32) | (unsigned long long)fx;
      int ca = (int)(((long long)a * CHK) / N);
      int cb = (int)(((long long)b * CHK) / N);
      atomicAdd(&dc2[(size_t)b * CHK + ca], pk);  // fwd a->b in (b, chunk(a))
      atomicAdd(&dc2[(size_t)a * CHK + cb], pk);  // rev b->a in (a, chunk(b))
    }
  }
  // --- GEMM: BM=32, BK=32, A+W in LDS ---
  const int r0 = blockIdx.x * 32;
  const int tc = t & 15, tr = t >> 4;
  const float* W0 = W;
  const float* W1 = W + (size_t)K * 64;
  const float* W2 = W + (size_t)2 * K * 64;
  float a1r[2][4] = {}, a1i[2][4] = {}, a2r[2][4] = {}, a2i[2][4] = {};
  float amr[2][4] = {}, ami[2][4] = {};
  for (int k0 = 0; k0 < K; k0 += 32) {
    {
      int row = t >> 3, c4 = t & 7;
      int gr = r0 + row;
      float4 fr = make_float4(0.f, 0.f, 0.f, 0.f), fi = fr;
      if (gr < M) {
        fr = ld4(&Ar[(size_t)gr * K + k0 + c4 * 4]);
        fi = ld4(&Ai[(size_t)gr * K + k0 + c4 * 4]);
      }
      *reinterpret_cast<float4*>(&Asr[row][c4 * 4]) = fr;
      *reinterpret_cast<float4*>(&Asi[row][c4 * 4]) = fi;
    }
    for (int li = t; li < 512; li += 256) {
      int row = li >> 4, c4 = li & 15;
      size_t woff = (size_t)(k0 + row) * 64 + c4 * 4;
      float4 w1 = ld4(&W1[woff]);
      float4 w2 = ld4(&W2[woff]);
      float4 w0 = ld4(&W0[woff]);
      *reinterpret_cast<float4*>(&Ws1[row][c4 * 4]) = w1;
      *reinterpret_cast<float4*>(&Ws2[row][c4 * 4]) = w2;
      *reinterpret_cast<float4*>(&Wsm[row][c4 * 4]) =
          make_float4(w0.x - w2.x, w0.y - w2.y, w0.z - w2.z, w0.w - w2.w);
    }
    __syncthreads();
#pragma unroll 4
    for (int k = 0; k < 32; ++k) {
      float4 b1 = *reinterpret_cast<const float4*>(&Ws1[k][tc * 4]);
      float4 b2 = *reinterpret_cast<const float4*>(&Ws2[k][tc * 4]);
      float4 bm = *reinterpret_cast<const float4*>(&Wsm[k][tc * 4]);
#pragma unroll
      for (int i = 0; i < 2; ++i) {
        float ar = Asr[tr * 2 + i][k], ai = Asi[tr * 2 + i][k];
        a1r[i][0] += ar * b1.x; a1r[i][1] += ar * b1.y; a1r[i][2] += ar * b1.z; a1r[i][3] += ar * b1.w;
        a1i[i][0] += ai * b1.x; a1i[i][1] += ai * b1.y; a1i[i][2] += ai * b1.z; a1i[i][3] += ai * b1.w;
        a2r[i][0] += ar * b2.x; a2r[i][1] += ar * b2.y; a2r[i][2] += ar * b2.z; a2r[i][3] += ar * b2.w;
        a2i[i][0] += ai * b2.x; a2i[i][1] += ai * b2.y; a2i[i][2] += ai * b2.z; a2i[i][3] += ai * b2.w;
        amr[i][0] += ar * bm.x; amr[i][1] += ar * bm.y; amr[i][2] += ar * bm.z; amr[i][3] += ar * bm.w;
        ami[i][0] += ai * bm.x; ami[i][1] += ai * bm.y; ami[i][2] += ai * bm.z; ami[i][3] += ai * bm.w;
      }
    }
    __syncthreads();
  }
  float b0 = bias[tc * 4 + 0], bb1 = bias[tc * 4 + 1];
  float b2v = bias[tc * 4 + 2], b3 = bias[tc * 4 + 3];
#pragma unroll
  for (int i = 0; i < 2; ++i) {
    int gr = r0 + tr * 2 + i;
    if (gr >= M) continue;
    size_t pb = (size_t)gr * 128 + tc * 8;
    *reinterpret_cast<float4*>(&P1[pb]) =
        make_float4(a1r[i][0], a1i[i][0], a1r[i][1], a1i[i][1]);
    *reinterpret_cast<float4*>(&P1[pb + 4]) =
        make_float4(a1r[i][2], a1i[i][2], a1r[i][3], a1i[i][3]);
    *reinterpret_cast<float4*>(&P2[pb]) =
        make_float4(a2r[i][0], a2i[i][0], a2r[i][1], a2i[i][1]);
    *reinterpret_cast<float4*>(&P2[pb + 4]) =
        make_float4(a2r[i][2], a2i[i][2], a2r[i][3], a2i[i][3]);
    size_t hb = (size_t)gr * 64 + tc * 4;
    *reinterpret_cast<float4*>(&Hr[hb]) =
        make_float4(amr[i][0] - ami[i][0] + b0, amr[i][1] - ami[i][1] + bb1,
                    amr[i][2] - ami[i][2] + b2v, amr[i][3] - ami[i][3] + b3);
    *reinterpret_cast<float4*>(&Hi[hb]) =
        make_float4(amr[i][0] + ami[i][0] + b0, amr[i][1] + ami[i][1] + bb1,
                    amr[i][2] + ami[i][2] + b2v, amr[i][3] + ami[i][3] + b3);
  }
}

// ---- standalone GEMM (layer 2) ----------------------------------------------
template <int K>
__global__ __launch_bounds__(256) void k_gemmF(
    const float* __restrict__ Ar, const float* __restrict__ Ai,
    const float* __restrict__ W, const float* __restrict__ bias,
    float* __restrict__ P1, float* __restrict__ P2,
    float* __restrict__ Hr, float* __restrict__ Hi, int M) {
  __shared__ float Asr[32][36];
  __shared__ float Asi[32][36];
  __shared__ float Ws1[32][64];
  __shared__ float Ws2[32][64];
  __shared__ float Wsm[32][64];
  const int t = threadIdx.x;
  const int r0 = blockIdx.x * 32;
  const int tc = t & 15, tr = t >> 4;
  const float* W0 = W;
  const float* W1 = W + (size_t)K * 64;
  const float* W2 = W + (size_t)2 * K * 64;
  float a1r[2][4] = {}, a1i[2][4] = {}, a2r[2][4] = {}, a2i[2][4] = {};
  float amr[2][4] = {}, ami[2][4] = {};
  for (int k0 = 0; k0 < K; k0 += 32) {
    {
      int row = t >> 3, c4 = t & 7;
      int gr = r0 + row;
      float4 fr = make_float4(0.f, 0.f, 0.f, 0.f), fi = fr;
      if (gr < M) {
        fr = ld4(&Ar[(size_t)gr * K + k0 + c4 * 4]);
        fi = ld4(&Ai[(size_t)gr * K + k0 + c4 * 4]);
      }
      *reinterpret_cast<float4*>(&Asr[row][c4 * 4]) = fr;
      *reinterpret_cast<float4*>(&Asi[row][c4 * 4]) = fi;
    }
    for (int li = t; li < 512; li += 256) {
      int row = li >> 4, c4 = li & 15;
      size_t woff = (size_t)(k0 + row) * 64 + c4 * 4;
      float4 w1 = ld4(&W1[woff]);
      float4 w2 = ld4(&W2[woff]);
      float4 w0 = ld4(&W0[woff]);
      *reinterpret_cast<float4*>(&Ws1[row][c4 * 4]) = w1;
      *reinterpret_cast<float4*>(&Ws2[row][c4 * 4]) = w2;
      *reinterpret_cast<float4*>(&Wsm[row][c4 * 4]) =
          make_float4(w0.x - w2.x, w0.y - w2.y, w0.z - w2.z, w0.w - w2.w);
    }
    __syncthreads();
#pragma unroll 4
    for (int k = 0; k < 32; ++k) {
      float4 b1 = *reinterpret_cast<const float4*>(&Ws1[k][tc * 4]);
      float4 b2 = *reinterpret_cast<const float4*>(&Ws2[k][tc * 4]);
      float4 bm = *reinterpret_cast<const float4*>(&Wsm[k][tc * 4]);
#pragma unroll
      for (int i = 0; i < 2; ++i) {
        float ar = Asr[tr * 2 + i][k], ai = Asi[tr * 2 + i][k];
        a1r[i][0] += ar * b1.x; a1r[i][1] += ar * b1.y; a1r[i][2] += ar * b1.z; a1r[i][3] += ar * b1.w;
        a1i[i][0] += ai * b1.x; a1i[i][1] += ai * b1.y; a1i[i][2] += ai * b1.z; a1i[i][3] += ai * b1.w;
        a2r[i][0] += ar * b2.x; a2r[i][1] += ar * b2.y; a2r[i][2] += ar * b2.z; a2r[i][3] += ar * b2.w;
        a2i[i][0] += ai * b2.x; a2i[i][1] += ai * b2.y; a2i[i][2] += ai * b2.z; a2i[i][3] += ai * b2.w;
        amr[i][0] += ar * bm.x; amr[i][1] += ar * bm.y; amr[i][2] += ar * bm.z; amr[i][3] += ar * bm.w;
        ami[i][0] += ai * bm.x; ami[i][1] += ai * bm.y; ami[i][2] += ai * bm.z; ami[i][3] += ai * bm.w;
      }
    }
    __syncthreads();
  }
  float b0 = bias[tc * 4 + 0], bb1 = bias[tc * 4 + 1];
  float b2v = bias[tc * 4 + 2], b3 = bias[tc * 4 + 3];
#pragma unroll
  for (int i = 0; i < 2; ++i) {
    int gr = r0 + tr * 2 + i;
    if (gr >= M) continue;
    size_t pb = (size_t)gr * 128 + tc * 8;
    *reinterpret_cast<float4*>(&P1[pb]) =
        make_float4(a1r[i][0], a1i[i][0], a1r[i][1], a1i[i][1]);
    *reinterpret_cast<float4*>(&P1[pb + 4]) =
        make_float4(a1r[i][2], a1i[i][2], a1r[i][3], a1i[i][3]);
    *reinterpret_cast<float4*>(&P2[pb]) =
        make_float4(a2r[i][0], a2i[i][0], a2r[i][1], a2i[i][1]);
    *reinterpret_cast<float4*>(&P2[pb + 4]) =
        make_float4(a2r[i][2], a2i[i][2], a2r[i][3], a2i[i][3]);
    size_t hb = (size_t)gr * 64 + tc * 4;
    *reinterpret_cast<float4*>(&Hr[hb]) =
        make_float4(amr[i][0] - ami[i][0] + b0, amr[i][1] - ami[i][1] + bb1,
                    amr[i][2] - ami[i][2] + b2v, amr[i][3] - ami[i][3] + b3);
    *reinterpret_cast<float4*>(&Hi[hb]) =
        make_float4(amr[i][0] + ami[i][0] + b0, amr[i][1] + ami[i][1] + bb1,
                    amr[i][2] + ami[i][2] + b2v, amr[i][3] + ami[i][3] + b3);
  }
}

// ---- scan1: exclusive scan of bucket counts; also extracts deg[node] --------
__global__ __launch_bounds__(256) void k_scan1(
    const unsigned long long* __restrict__ dc2, int* __restrict__ rp2,
    int* __restrict__ bsum, float* __restrict__ deg, int NC) {
  __shared__ int sh[256];
  int t = threadIdx.x;
  int base = blockIdx.x * 1024 + t * 4;
  unsigned long long e0 = (base + 0 < NC) ? dc2[base + 0] : 0ULL;
  unsigned long long e1 = (base + 1 < NC) ? dc2[base + 1] : 0ULL;
  unsigned long long e2 = (base + 2 < NC) ? dc2[base + 2] : 0ULL;
  unsigned long long e3 = (base + 3 < NC) ? dc2[base + 3] : 0ULL;
  int c0 = (int)(e0 >> 32), c1 = (int)(e1 >> 32);
  int c2 = (int)(e2 >> 32), c3 = (int)(e3 >> 32);
  // deg[node] = sum of the node's 16 bucket low-words (4 threads x 4 entries)
  unsigned long long l = (unsigned)e0 + (unsigned)e1 + (unsigned)e2 + (unsigned)e3;
  l += __shfl_xor(l, 1);
  l += __shfl_xor(l, 2);
  if ((t & 3) == 0 && base < NC)
    deg[base >> 4] = (float)l * (1.f / 16777216.f);
  int s = c0 + c1 + c2 + c3;
  sh[t] = s;
  __syncthreads();
  for (int o = 1; o < 256; o <<= 1) {
    int y = (t >= o) ? sh[t - o] : 0;
    __syncthreads();
    if (t >= o) sh[t] += y;
    __syncthreads();
  }
  int excl = sh[t] - s;
  if (base + 0 < NC) rp2[base + 0] = excl;
  if (base + 1 < NC) rp2[base + 1] = excl + c0;
  if (base + 2 < NC) rp2[base + 2] = excl + c0 + c1;
  if (base + 3 < NC) rp2[base + 3] = excl + c0 + c1 + c2;
  if (t == 255) bsum[blockIdx.x] = sh[255];
}

// ---- scan3: add block-sum prefix, copy to nxt2 ------------------------------
__global__ void k_scan3(int* __restrict__ rp2, int* __restrict__ nxt2,
                        const int* __restrict__ bsum, int NC, int twoE) {
  int i = blockIdx.x * 256 + threadIdx.x;
  if (i > NC) return;
  if (i == NC) { rp2[NC] = twoE; return; }
  int b = i >> 10;
  int pre = 0;
  for (int j = 0; j < b; ++j) pre += bsum[j];  // wave-uniform loop
  int val = rp2[i] + pre;
  rp2[i] = val;
  nxt2[i] = val;
}

// ---- scatter into (dst, src-chunk) buckets ----------------------------------
__global__ void k_scatter(const int* __restrict__ u, const int* __restrict__ v,
                          const float* __restrict__ w,
                          const float* __restrict__ deg,
                          int* __restrict__ nxt2, int* __restrict__ src,
                          float2* __restrict__ cf, int E, int N) {
  int e = blockIdx.x * 256 + threadIdx.x;
  if (e >= E) return;
  int a = u[e], b = v[e];
  float we = w[e];
  float da = deg[a], db = deg[b];
  float ia = da > 0.f ? rsqrtf(da) : 0.f;
  float ib = db > 0.f ? rsqrtf(db) : 0.f;
  float norm = ia * (0.5f * we) * ib;
  float th = 1.57079632679489662f * we;  // 2*pi*q*w, q=0.25
  float sn, cs;
  sincosf(th, &sn, &cs);
  float cr = -norm * cs, ci = -norm * sn;
  int ca = (int)(((long long)a * CHK) / N);
  int cb = (int)(((long long)b * CHK) / N);
  int p1 = atomicAdd(&nxt2[b * CHK + ca], 1);  // fwd a->b, coeff (cr, ci)
  src[p1] = a;
  cf[p1] = make_float2(cr, ci);
  int p2 = atomicAdd(&nxt2[a * CHK + cb], 1);  // rev b->a, coeff (cr, -ci)
  src[p2] = b;
  cf[p2] = make_float2(cr, -ci);
}

// ---- gU: chunk-major, 4 dests/wave, full-wave-per-edge (lane = feature) -----
// Z[d] = [ (g1r+2u0, g1i+2u1) pairs (128 f) | (g1r+2u2, g1i+2u3) pairs ]
__global__ __launch_bounds__(256) void k_gU(
    const int* __restrict__ src, const float2* __restrict__ cf,
    const int* __restrict__ rp2, const float* __restrict__ P2,
    const float* __restrict__ P1, float* __restrict__ Z, int N) {
  int wave = threadIdx.x >> 6;
  int lane = threadIdx.x & 63;
  int d0 = (blockIdx.x * 4 + wave) * 4;
  int bnd[4];
#pragma unroll
  for (int j = 0; j < 4; ++j)
    bnd[j] = (lane < 17 && d0 + j < N) ? rp2[(d0 + j) * CHK + lane] : 0;
  float u0[4] = {}, u1[4] = {}, u2[4] = {}, u3[4] = {};
  for (int c = 0; c < CHK; ++c) {
#pragma unroll
    for (int j = 0; j < 4; ++j) {
      int k0 = __shfl(bnd[j], c);
      int k1 = __shfl(bnd[j], c + 1);
      for (int k = k0; k < k1; ++k) {
        int s = src[k];           // wave-uniform
        float2 cc = cf[k];
        float2 g2 = ld2(P2 + (size_t)s * 128 + lane * 2);
        u0[j] += cc.x * g2.x; u1[j] += cc.y * g2.y;
        u2[j] += cc.y * g2.x; u3[j] += cc.x * g2.y;
      }
    }
  }
#pragma unroll
  for (int j = 0; j < 4; ++j) {
    int d = d0 + j;
    if (d >= N) continue;
    float2 p = ld2(P1 + (size_t)d * 128 + lane * 2);
    *reinterpret_cast<float2*>(&Z[(size_t)d * 256 + lane * 2]) =
        make_float2(p.x + 2.f * u0[j], p.y + 2.f * u1[j]);
    *reinterpret_cast<float2*>(&Z[(size_t)d * 256 + 128 + lane * 2]) =
        make_float2(p.x + 2.f * u2[j], p.y + 2.f * u3[j]);
  }
}

// ---- gC: chunk-major, 4 dests/wave, full-wave-per-edge ----------------------
// lanes 0-31 accumulate hr from z1-half; lanes 32-63 accumulate hi from z2.
__global__ __launch_bounds__(256) void k_gC(
    const int* __restrict__ src, const float2* __restrict__ cf,
    const int* __restrict__ rp2, const float* __restrict__ Z,
    float* __restrict__ Hr, float* __restrict__ Hi, int N) {
  int wave = threadIdx.x >> 6;
  int lane = threadIdx.x & 63;
  int g = lane >> 5, lg = lane & 31;
  int d0 = (blockIdx.x * 4 + wave) * 4;
  int bnd[4];
#pragma unroll
  for (int j = 0; j < 4; ++j)
    bnd[j] = (lane < 17 && d0 + j < N) ? rp2[(d0 + j) * CHK + lane] : 0;
  float2 acc[4] = {};
  const size_t half = (size_t)g * 128;
  for (int c = 0; c < CHK; ++c) {
#pragma unroll
    for (int j = 0; j < 4; ++j) {
      int k0 = __shfl(bnd[j], c);
      int k1 = __shfl(bnd[j], c + 1);
      for (int k = k0; k < k1; ++k) {
        int s = src[k];
        float2 cc = cf[k];
        float4 z = ld4(Z + (size_t)s * 256 + half + lg * 4);
        float cA = g ? cc.y : cc.x;
        float cB = g ? cc.x : -cc.y;
        acc[j].x += cA * z.x + cB * z.y;
        acc[j].y += cA * z.z + cB * z.w;
      }
    }
  }
#pragma unroll
  for (int j = 0; j < 4; ++j) {
    int d = d0 + j;
    if (d >= N) continue;
    size_t hb = (size_t)d * 64 + lg * 2;
    float2 base = g ? ld2(&Hi[hb]) : ld2(&Hr[hb]);
    float2 mine = make_float2(base.x + acc[j].x, base.y + acc[j].y);
    float2 other;
    other.x = __shfl_xor(mine.x, 32);
    other.y = __shfl_xor(mine.y, 32);
    float2 hr = g ? other : mine;   // real part for the ReLU mask
    float2 out = mine;
    if (hr.x < 0.f) out.x = 0.f;
    if (hr.y < 0.f) out.y = 0.f;
    if (g == 0)
      *reinterpret_cast<float2*>(&Hr[hb]) = out;
    else
      *reinterpret_cast<float2*>(&Hi[hb]) = out;
  }
}

// ---- query gather + linear + log_softmax ------------------------------------
__global__ __launch_bounds__(256) void k_query(
    const int* __restrict__ qe, const float* __restrict__ xr,
    const float* __restrict__ xi, const float* __restrict__ Wlin,
    const float* __restrict__ blin, float* __restrict__ out, int Q) {
  int q = blockIdx.x * 4 + (threadIdx.x >> 6);
  if (q >= Q) return;
  int lane = threadIdx.x & 63;
  int q0 = qe[2 * q], q1 = qe[2 * q + 1];
  float x0 = xr[(size_t)q0 * 64 + lane];
  float x1 = xr[(size_t)q1 * 64 + lane];
  float x2 = xi[(size_t)q0 * 64 + lane];
  float x3 = xi[(size_t)q1 * 64 + lane];
  float l0 = x0 * Wlin[lane] + x1 * Wlin[64 + lane] + x2 * Wlin[128 + lane] + x3 * Wlin[192 + lane];
  float l1 = x0 * Wlin[256 + lane] + x1 * Wlin[320 + lane] + x2 * Wlin[384 + lane] + x3 * Wlin[448 + lane];
#pragma unroll
  for (int o = 32; o > 0; o >>= 1) {
    l0 += __shfl_xor(l0, o);
    l1 += __shfl_xor(l1, o);
  }
  if (lane == 0) {
    l0 += blin[0];
    l1 += blin[1];
    float m = fmaxf(l0, l1);
    float lse = m + logf(expf(l0 - m) + expf(l1 - m));
    out[2 * q + 0] = l0 - lse;
    out[2 * q + 1] = l1 - lse;
  }
}

extern "C" void kernel_launch(void* const* d_in, const int* in_sizes, int n_in,
                              void* d_out, int out_size, void* d_ws, size_t ws_size,
                              hipStream_t stream) {
  const float* real = (const float*)d_in[0];
  const float* imag = (const float*)d_in[1];
  const int* ei     = (const int*)d_in[2];
  const int* qe     = (const int*)d_in[3];
  const float* ew   = (const float*)d_in[4];
  const float* W1   = (const float*)d_in[5];
  const float* b1   = (const float*)d_in[6];
  const float* W2   = (const float*)d_in[7];
  const float* b2   = (const float*)d_in[8];
  const float* Wlin = (const float*)d_in[9];
  const float* blin = (const float*)d_in[10];

  const int N = in_sizes[0] / 128;
  const int E = in_sizes[4];
  const int Q = in_sizes[3] / 2;
  const int* u = ei;
  const int* v = ei + E;
  const int NC = N * CHK;

  float* ws = (float*)d_ws;
  size_t off = 0;
  auto alloc = [&](size_t n) { float* p = ws + off; off += n; return p; };
  const size_t N64 = (size_t)N * 64;
  const size_t N128 = (size_t)N * 128;
  const size_t N256 = (size_t)N * 256;

  float2* cf = (float2*)alloc((size_t)2 * E * 2);                 // 8B-aligned
  unsigned long long* dc2 = (unsigned long long*)alloc((size_t)2 * NC);
  int* src  = (int*)alloc((size_t)2 * E);
  float* P1  = alloc(N128);
  float* P2  = alloc(N128);
  float* Z   = alloc(N256);
  float* HAr = alloc(N64);
  float* HAi = alloc(N64);
  float* HBr = alloc(N64);
  float* HBi = alloc(N64);
  float* deg = alloc(N);
  int* rp2  = (int*)alloc(NC + 1);
  int* nxt2 = (int*)alloc(NC);
  int* bsum = (int*)alloc(1024);
  (void)ws_size; (void)n_in; (void)out_size;

  const int eb = (E + 255) / 256;
  const int mb = (N + 31) / 32;
  const int NB = (NC + 1023) / 1024;
  const int gbW = (N + 15) / 16;
  const int epb = (E + mb - 1) / mb;

  // --- dispatch 1: layer-1 GEMM with bucket-count/deg atomic prefix ---
  hipMemsetAsync(dc2, 0, (size_t)NC * 8, stream);
  k_gemm_deg<128><<<mb, 256, 0, stream>>>(
      u, v, ew, dc2, E, epb, N, real, imag, W1, b1, P1, P2, HAr, HAi, N);
  // --- 2-level CSR ---
  k_scan1<<<NB, 256, 0, stream>>>(dc2, rp2, bsum, deg, NC);
  k_scan3<<<(NC + 256) / 256, 256, 0, stream>>>(rp2, nxt2, bsum, NC, 2 * E);
  k_scatter<<<eb, 256, 0, stream>>>(u, v, ew, deg, nxt2, src, cf, E, N);

  // --- layer 1 sparse ---
  k_gU<<<gbW, 256, 0, stream>>>(src, cf, rp2, P2, P1, Z, N);
  k_gC<<<gbW, 256, 0, stream>>>(src, cf, rp2, Z, HAr, HAi, N);

  // --- layer 2 ---
  k_gemmF<64><<<mb, 256, 0, stream>>>(HAr, HAi, W2, b2, P1, P2, HBr, HBi, N);
  k_gU<<<gbW, 256, 0, stream>>>(src, cf, rp2, P2, P1, Z, N);
  k_gC<<<gbW, 256, 0, stream>>>(src, cf, rp2, Z, HBr, HBi, N);

  // --- queries ---
  k_query<<<(Q + 3) / 4, 256, 0, stream>>>(qe, HBr, HBi, Wlin, blin, (float*)d_out, Q);
}

// Round 14
// 673.606 us; speedup vs baseline: 1.2837x; 1.1960x over previous
//
#include <hip/hip_runtime.h>

// ---------------------------------------------------------------------------
// MagNet link prediction forward, f32 (16-bit quant of propagated streams
// fails: complex-ReLU mask flips amplify tiny hr errors — rounds 3/4).
// Gather (CSR), telescoped Chebyshev: out = x@(W0-W2)+b + prop(g1+2*prop(g2)).
// FINAL (round-11 optimum, reverted after chunk-blocking rounds 12/13 proved
// the sparse passes are bound by the random row REQUEST path, not bytes:
// FETCH 485->364MB with zero time gain). Structure:
//  * deg_count fused as fire-and-forget u64-packed-atomic prefix slices
//    inside the layer-1 GEMM blocks (hides atomic latency under VALU work).
//  * 6-stream GEMM (BM=32, BK=32, A+W in LDS): P1=(g1r|g1i), P2=(g2r|g2i)
//    pairs + biased H bases in one pass.
//  * gU: prop(g2) u-streams + fused comb -> Z = [P1+2(u0,u1) | P1+2(u2,u3)].
//  * gC: single gather of 1KB Z rows -> hr,hi + complex ReLU inline.
// Sparse passes pinned at ~3.65 TB/s effective across 6 structural variants
// (rounds 2-13); bytes at the 1.5KB/edge/layer algebraic minimum.
// ---------------------------------------------------------------------------

__device__ __forceinline__ float4 ld4(const float* __restrict__ p) {
  return *reinterpret_cast<const float4*>(p);
}
__device__ __forceinline__ float2 ld2(const float* __restrict__ p) {
  return *reinterpret_cast<const float2*>(p);
}

// ---- fused: [edge-slice deg atomics prefix] + 6-stream GEMM (layer 1) -------
template <int K>
__global__ __launch_bounds__(256) void k_gemm_deg(
    const int* __restrict__ u, const int* __restrict__ v,
    const float* __restrict__ w, unsigned long long* __restrict__ dc, int E,
    int epb,
    const float* __restrict__ Ar, const float* __restrict__ Ai,
    const float* __restrict__ W,  // [3][K][64]
    const float* __restrict__ bias,
    float* __restrict__ P1, float* __restrict__ P2,
    float* __restrict__ Hr, float* __restrict__ Hi, int M) {
  __shared__ float Asr[32][36];
  __shared__ float Asi[32][36];
  __shared__ float Ws1[32][64];
  __shared__ float Ws2[32][64];
  __shared__ float Wsm[32][64];
  const int t = threadIdx.x;
  {  // --- deg prefix: fire-and-forget packed atomics, no dependent reads ---
    int e0 = blockIdx.x * epb;
    int e1 = min(e0 + epb, E);
    for (int e = e0 + t; e < e1; e += 256) {
      float hw = 0.5f * w[e];
      unsigned fx = __float2uint_rn(hw * 16777216.f);  // 2^24 fixed point
      unsigned long long pk = (1ULL << 32) | (unsigned long long)fx;
      atomicAdd(&dc[u[e]], pk);
      atomicAdd(&dc[v[e]], pk);
    }
  }
  // --- GEMM: BM=32, BK=32, A+W in LDS ---
  const int r0 = blockIdx.x * 32;
  const int tc = t & 15, tr = t >> 4;
  const float* W0 = W;
  const float* W1 = W + (size_t)K * 64;
  const float* W2 = W + (size_t)2 * K * 64;
  float a1r[2][4] = {}, a1i[2][4] = {}, a2r[2][4] = {}, a2i[2][4] = {};
  float amr[2][4] = {}, ami[2][4] = {};
  for (int k0 = 0; k0 < K; k0 += 32) {
    {  // A tile: 32 rows x 8 float4, one per thread per array
      int row = t >> 3, c4 = t & 7;
      int gr = r0 + row;
      float4 fr = make_float4(0.f, 0.f, 0.f, 0.f), fi = fr;
      if (gr < M) {
        fr = ld4(&Ar[(size_t)gr * K + k0 + c4 * 4]);
        fi = ld4(&Ai[(size_t)gr * K + k0 + c4 * 4]);
      }
      *reinterpret_cast<float4*>(&Asr[row][c4 * 4]) = fr;
      *reinterpret_cast<float4*>(&Asi[row][c4 * 4]) = fi;
    }
    for (int li = t; li < 512; li += 256) {  // W tiles: 32 rows x 16 f4 each
      int row = li >> 4, c4 = li & 15;
      size_t woff = (size_t)(k0 + row) * 64 + c4 * 4;
      float4 w1 = ld4(&W1[woff]);
      float4 w2 = ld4(&W2[woff]);
      float4 w0 = ld4(&W0[woff]);
      *reinterpret_cast<float4*>(&Ws1[row][c4 * 4]) = w1;
      *reinterpret_cast<float4*>(&Ws2[row][c4 * 4]) = w2;
      *reinterpret_cast<float4*>(&Wsm[row][c4 * 4]) =
          make_float4(w0.x - w2.x, w0.y - w2.y, w0.z - w2.z, w0.w - w2.w);
    }
    __syncthreads();
#pragma unroll 4
    for (int k = 0; k < 32; ++k) {
      float4 b1 = *reinterpret_cast<const float4*>(&Ws1[k][tc * 4]);
      float4 b2 = *reinterpret_cast<const float4*>(&Ws2[k][tc * 4]);
      float4 bm = *reinterpret_cast<const float4*>(&Wsm[k][tc * 4]);
#pragma unroll
      for (int i = 0; i < 2; ++i) {
        float ar = Asr[tr * 2 + i][k], ai = Asi[tr * 2 + i][k];
        a1r[i][0] += ar * b1.x; a1r[i][1] += ar * b1.y; a1r[i][2] += ar * b1.z; a1r[i][3] += ar * b1.w;
        a1i[i][0] += ai * b1.x; a1i[i][1] += ai * b1.y; a1i[i][2] += ai * b1.z; a1i[i][3] += ai * b1.w;
        a2r[i][0] += ar * b2.x; a2r[i][1] += ar * b2.y; a2r[i][2] += ar * b2.z; a2r[i][3] += ar * b2.w;
        a2i[i][0] += ai * b2.x; a2i[i][1] += ai * b2.y; a2i[i][2] += ai * b2.z; a2i[i][3] += ai * b2.w;
        amr[i][0] += ar * bm.x; amr[i][1] += ar * bm.y; amr[i][2] += ar * bm.z; amr[i][3] += ar * bm.w;
        ami[i][0] += ai * bm.x; ami[i][1] += ai * bm.y; ami[i][2] += ai * bm.z; ami[i][3] += ai * bm.w;
      }
    }
    __syncthreads();
  }
  float b0 = bias[tc * 4 + 0], bb1 = bias[tc * 4 + 1];
  float b2v = bias[tc * 4 + 2], b3 = bias[tc * 4 + 3];
#pragma unroll
  for (int i = 0; i < 2; ++i) {
    int gr = r0 + tr * 2 + i;
    if (gr >= M) continue;
    size_t pb = (size_t)gr * 128 + tc * 8;  // feature pairs f=4tc..4tc+3
    *reinterpret_cast<float4*>(&P1[pb]) =
        make_float4(a1r[i][0], a1i[i][0], a1r[i][1], a1i[i][1]);
    *reinterpret_cast<float4*>(&P1[pb + 4]) =
        make_float4(a1r[i][2], a1i[i][2], a1r[i][3], a1i[i][3]);
    *reinterpret_cast<float4*>(&P2[pb]) =
        make_float4(a2r[i][0], a2i[i][0], a2r[i][1], a2i[i][1]);
    *reinterpret_cast<float4*>(&P2[pb + 4]) =
        make_float4(a2r[i][2], a2i[i][2], a2r[i][3], a2i[i][3]);
    size_t hb = (size_t)gr * 64 + tc * 4;
    *reinterpret_cast<float4*>(&Hr[hb]) =
        make_float4(amr[i][0] - ami[i][0] + b0, amr[i][1] - ami[i][1] + bb1,
                    amr[i][2] - ami[i][2] + b2v, amr[i][3] - ami[i][3] + b3);
    *reinterpret_cast<float4*>(&Hi[hb]) =
        make_float4(amr[i][0] + ami[i][0] + b0, amr[i][1] + ami[i][1] + bb1,
                    amr[i][2] + ami[i][2] + b2v, amr[i][3] + ami[i][3] + b3);
  }
}

// ---- standalone GEMM (layer 2) ----------------------------------------------
template <int K>
__global__ __launch_bounds__(256) void k_gemmF(
    const float* __restrict__ Ar, const float* __restrict__ Ai,
    const float* __restrict__ W, const float* __restrict__ bias,
    float* __restrict__ P1, float* __restrict__ P2,
    float* __restrict__ Hr, float* __restrict__ Hi, int M) {
  __shared__ float Asr[32][36];
  __shared__ float Asi[32][36];
  __shared__ float Ws1[32][64];
  __shared__ float Ws2[32][64];
  __shared__ float Wsm[32][64];
  const int t = threadIdx.x;
  const int r0 = blockIdx.x * 32;
  const int tc = t & 15, tr = t >> 4;
  const float* W0 = W;
  const float* W1 = W + (size_t)K * 64;
  const float* W2 = W + (size_t)2 * K * 64;
  float a1r[2][4] = {}, a1i[2][4] = {}, a2r[2][4] = {}, a2i[2][4] = {};
  float amr[2][4] = {}, ami[2][4] = {};
  for (int k0 = 0; k0 < K; k0 += 32) {
    {
      int row = t >> 3, c4 = t & 7;
      int gr = r0 + row;
      float4 fr = make_float4(0.f, 0.f, 0.f, 0.f), fi = fr;
      if (gr < M) {
        fr = ld4(&Ar[(size_t)gr * K + k0 + c4 * 4]);
        fi = ld4(&Ai[(size_t)gr * K + k0 + c4 * 4]);
      }
      *reinterpret_cast<float4*>(&Asr[row][c4 * 4]) = fr;
      *reinterpret_cast<float4*>(&Asi[row][c4 * 4]) = fi;
    }
    for (int li = t; li < 512; li += 256) {
      int row = li >> 4, c4 = li & 15;
      size_t woff = (size_t)(k0 + row) * 64 + c4 * 4;
      float4 w1 = ld4(&W1[woff]);
      float4 w2 = ld4(&W2[woff]);
      float4 w0 = ld4(&W0[woff]);
      *reinterpret_cast<float4*>(&Ws1[row][c4 * 4]) = w1;
      *reinterpret_cast<float4*>(&Ws2[row][c4 * 4]) = w2;
      *reinterpret_cast<float4*>(&Wsm[row][c4 * 4]) =
          make_float4(w0.x - w2.x, w0.y - w2.y, w0.z - w2.z, w0.w - w2.w);
    }
    __syncthreads();
#pragma unroll 4
    for (int k = 0; k < 32; ++k) {
      float4 b1 = *reinterpret_cast<const float4*>(&Ws1[k][tc * 4]);
      float4 b2 = *reinterpret_cast<const float4*>(&Ws2[k][tc * 4]);
      float4 bm = *reinterpret_cast<const float4*>(&Wsm[k][tc * 4]);
#pragma unroll
      for (int i = 0; i < 2; ++i) {
        float ar = Asr[tr * 2 + i][k], ai = Asi[tr * 2 + i][k];
        a1r[i][0] += ar * b1.x; a1r[i][1] += ar * b1.y; a1r[i][2] += ar * b1.z; a1r[i][3] += ar * b1.w;
        a1i[i][0] += ai * b1.x; a1i[i][1] += ai * b1.y; a1i[i][2] += ai * b1.z; a1i[i][3] += ai * b1.w;
        a2r[i][0] += ar * b2.x; a2r[i][1] += ar * b2.y; a2r[i][2] += ar * b2.z; a2r[i][3] += ar * b2.w;
        a2i[i][0] += ai * b2.x; a2i[i][1] += ai * b2.y; a2i[i][2] += ai * b2.z; a2i[i][3] += ai * b2.w;
        amr[i][0] += ar * bm.x; amr[i][1] += ar * bm.y; amr[i][2] += ar * bm.z; amr[i][3] += ar * bm.w;
        ami[i][0] += ai * bm.x; ami[i][1] += ai * bm.y; ami[i][2] += ai * bm.z; ami[i][3] += ai * bm.w;
      }
    }
    __syncthreads();
  }
  float b0 = bias[tc * 4 + 0], bb1 = bias[tc * 4 + 1];
  float b2v = bias[tc * 4 + 2], b3 = bias[tc * 4 + 3];
#pragma unroll
  for (int i = 0; i < 2; ++i) {
    int gr = r0 + tr * 2 + i;
    if (gr >= M) continue;
    size_t pb = (size_t)gr * 128 + tc * 8;
    *reinterpret_cast<float4*>(&P1[pb]) =
        make_float4(a1r[i][0], a1i[i][0], a1r[i][1], a1i[i][1]);
    *reinterpret_cast<float4*>(&P1[pb + 4]) =
        make_float4(a1r[i][2], a1i[i][2], a1r[i][3], a1i[i][3]);
    *reinterpret_cast<float4*>(&P2[pb]) =
        make_float4(a2r[i][0], a2i[i][0], a2r[i][1], a2i[i][1]);
    *reinterpret_cast<float4*>(&P2[pb + 4]) =
        make_float4(a2r[i][2], a2i[i][2], a2r[i][3], a2i[i][3]);
    size_t hb = (size_t)gr * 64 + tc * 4;
    *reinterpret_cast<float4*>(&Hr[hb]) =
        make_float4(amr[i][0] - ami[i][0] + b0, amr[i][1] - ami[i][1] + bb1,
                    amr[i][2] - ami[i][2] + b2v, amr[i][3] - ami[i][3] + b3);
    *reinterpret_cast<float4*>(&Hi[hb]) =
        make_float4(amr[i][0] + ami[i][0] + b0, amr[i][1] + ami[i][1] + bb1,
                    amr[i][2] + ami[i][2] + b2v, amr[i][3] + ami[i][3] + b3);
  }
}

// ---- exclusive scan of cnt (= dc>>32) -> rp ---------------------------------
__global__ __launch_bounds__(256) void k_scan1(
    const unsigned long long* __restrict__ dc, int* __restrict__ rp,
    int* __restrict__ bsum, int N) {
  __shared__ int sh[256];
  int t = threadIdx.x;
  int base = blockIdx.x * 1024 + t * 4;
  int c0 = (base + 0 < N) ? (int)(dc[base + 0] >> 32) : 0;
  int c1 = (base + 1 < N) ? (int)(dc[base + 1] >> 32) : 0;
  int c2 = (base + 2 < N) ? (int)(dc[base + 2] >> 32) : 0;
  int c3 = (base + 3 < N) ? (int)(dc[base + 3] >> 32) : 0;
  int s = c0 + c1 + c2 + c3;
  sh[t] = s;
  __syncthreads();
  for (int o = 1; o < 256; o <<= 1) {
    int y = (t >= o) ? sh[t - o] : 0;
    __syncthreads();
    if (t >= o) sh[t] += y;
    __syncthreads();
  }
  int excl = sh[t] - s;
  if (base + 0 < N) rp[base + 0] = excl;
  if (base + 1 < N) rp[base + 1] = excl + c0;
  if (base + 2 < N) rp[base + 2] = excl + c0 + c1;
  if (base + 3 < N) rp[base + 3] = excl + c0 + c1 + c2;
  if (t == 255) bsum[blockIdx.x] = sh[255];
}

// ---- scan3 with folded block-sum prefix -------------------------------------
__global__ void k_scan3(int* __restrict__ rp, int* __restrict__ nxt,
                        const int* __restrict__ bsum, int N, int twoE) {
  int i = blockIdx.x * 256 + threadIdx.x;
  if (i > N) return;
  if (i == N) { rp[N] = twoE; return; }
  int b = i >> 10;
  int pre = 0;
  for (int j = 0; j < b; ++j) pre += bsum[j];  // <=48 iters, wave-uniform
  int val = rp[i] + pre;
  rp[i] = val;
  nxt[i] = val;
}

// ---- scatter edge records: src[pos], cf[pos]=(cr,ci) ------------------------
__global__ void k_scatter(const int* __restrict__ u, const int* __restrict__ v,
                          const float* __restrict__ w,
                          const unsigned long long* __restrict__ dc,
                          int* __restrict__ nxt, int* __restrict__ src,
                          float2* __restrict__ cf, int E) {
  int e = blockIdx.x * 256 + threadIdx.x;
  if (e >= E) return;
  int a = u[e], b = v[e];
  float we = w[e];
  float da = (float)(unsigned)dc[a] * (1.f / 16777216.f);
  float db = (float)(unsigned)dc[b] * (1.f / 16777216.f);
  float ia = da > 0.f ? rsqrtf(da) : 0.f;
  float ib = db > 0.f ? rsqrtf(db) : 0.f;
  float norm = ia * (0.5f * we) * ib;
  float th = 1.57079632679489662f * we;  // 2*pi*q*w, q=0.25
  float sn, cs;
  sincosf(th, &sn, &cs);
  float cr = -norm * cs, ci = -norm * sn;
  int p1 = atomicAdd(&nxt[b], 1);  // forward a->b, coeff (cr, ci)
  src[p1] = a;
  cf[p1] = make_float2(cr, ci);
  int p2 = atomicAdd(&nxt[a], 1);  // reverse b->a, coeff (cr, -ci)
  src[p2] = b;
  cf[p2] = make_float2(cr, -ci);
}

// ---- gU: u-streams of prop(g2) + fused comb: Z = [P1+2*(u0,u1) | P1+2*(u2,u3)]
__global__ __launch_bounds__(256) void k_gU(
    const int* __restrict__ src, const float2* __restrict__ cf,
    const int* __restrict__ rp, const float* __restrict__ P2,
    const float* __restrict__ P1, float* __restrict__ Z, int N) {
  int d = blockIdx.x * 4 + (threadIdx.x >> 6);
  if (d >= N) return;
  int lane = threadIdx.x & 63;
  int g = lane >> 5, lg = lane & 31;
  float4 a01 = {0, 0, 0, 0};
  float4 a23 = {0, 0, 0, 0};
  int k1 = rp[d + 1];
#pragma unroll 2
  for (int k = rp[d] + g; k < k1; k += 2) {
    int s = src[k];
    float2 c = cf[k];
    float4 v = ld4(P2 + (size_t)s * 128 + lg * 4);
    a01.x += c.x * v.x; a01.y += c.y * v.y;
    a01.z += c.x * v.z; a01.w += c.y * v.w;
    a23.x += c.y * v.x; a23.y += c.x * v.y;
    a23.z += c.y * v.z; a23.w += c.x * v.w;
  }
  a01.x += __shfl_xor(a01.x, 32); a01.y += __shfl_xor(a01.y, 32);
  a01.z += __shfl_xor(a01.z, 32); a01.w += __shfl_xor(a01.w, 32);
  a23.x += __shfl_xor(a23.x, 32); a23.y += __shfl_xor(a23.y, 32);
  a23.z += __shfl_xor(a23.z, 32); a23.w += __shfl_xor(a23.w, 32);
  float4 p = ld4(P1 + (size_t)d * 128 + lg * 4);
  size_t zb = (size_t)d * 256 + lg * 4;
  if (g == 0)
    *reinterpret_cast<float4*>(&Z[zb]) =
        make_float4(p.x + 2.f * a01.x, p.y + 2.f * a01.y,
                    p.z + 2.f * a01.z, p.w + 2.f * a01.w);
  else
    *reinterpret_cast<float4*>(&Z[zb + 128]) =
        make_float4(p.x + 2.f * a23.x, p.y + 2.f * a23.y,
                    p.z + 2.f * a23.z, p.w + 2.f * a23.w);
}

// ---- gC: hr += cr*z1r - ci*z1i; hi += ci*z2r + cr*z2i; complex ReLU ---------
__global__ __launch_bounds__(256) void k_gC(
    const int* __restrict__ src, const float2* __restrict__ cf,
    const int* __restrict__ rp, const float* __restrict__ Z,
    float* __restrict__ Hr, float* __restrict__ Hi, int N) {
  int d = blockIdx.x * 4 + (threadIdx.x >> 6);
  if (d >= N) return;
  int lane = threadIdx.x & 63;
  int g = lane >> 5, lg = lane & 31;
  float2 ahr = {0, 0}, ahi = {0, 0};
  int k1 = rp[d + 1];
#pragma unroll 2
  for (int k = rp[d] + g; k < k1; k += 2) {
    int s = src[k];
    float2 c = cf[k];
    const float* row = Z + (size_t)s * 256 + lg * 4;
    float4 z1 = ld4(row);
    float4 z2 = ld4(row + 128);
    ahr.x += c.x * z1.x - c.y * z1.y;
    ahr.y += c.x * z1.z - c.y * z1.w;
    ahi.x += c.y * z2.x + c.x * z2.y;
    ahi.y += c.y * z2.z + c.x * z2.w;
  }
  ahr.x += __shfl_xor(ahr.x, 32);
  ahr.y += __shfl_xor(ahr.y, 32);
  ahi.x += __shfl_xor(ahi.x, 32);
  ahi.y += __shfl_xor(ahi.y, 32);
  if (g == 0) {
    size_t hb = (size_t)d * 64 + lg * 2;
    float2 hr = ld2(&Hr[hb]);
    float2 hi = ld2(&Hi[hb]);
    hr.x += ahr.x; hr.y += ahr.y;
    hi.x += ahi.x; hi.y += ahi.y;
    if (hr.x < 0.f) { hr.x = 0.f; hi.x = 0.f; }
    if (hr.y < 0.f) { hr.y = 0.f; hi.y = 0.f; }
    *reinterpret_cast<float2*>(&Hr[hb]) = hr;
    *reinterpret_cast<float2*>(&Hi[hb]) = hi;
  }
}

// ---- query gather + linear + log_softmax ------------------------------------
__global__ __launch_bounds__(256) void k_query(
    const int* __restrict__ qe, const float* __restrict__ xr,
    const float* __restrict__ xi, const float* __restrict__ Wlin,
    const float* __restrict__ blin, float* __restrict__ out, int Q) {
  int q = blockIdx.x * 4 + (threadIdx.x >> 6);
  if (q >= Q) return;
  int lane = threadIdx.x & 63;
  int q0 = qe[2 * q], q1 = qe[2 * q + 1];
  float x0 = xr[(size_t)q0 * 64 + lane];
  float x1 = xr[(size_t)q1 * 64 + lane];
  float x2 = xi[(size_t)q0 * 64 + lane];
  float x3 = xi[(size_t)q1 * 64 + lane];
  float l0 = x0 * Wlin[lane] + x1 * Wlin[64 + lane] + x2 * Wlin[128 + lane] + x3 * Wlin[192 + lane];
  float l1 = x0 * Wlin[256 + lane] + x1 * Wlin[320 + lane] + x2 * Wlin[384 + lane] + x3 * Wlin[448 + lane];
#pragma unroll
  for (int o = 32; o > 0; o >>= 1) {
    l0 += __shfl_xor(l0, o);
    l1 += __shfl_xor(l1, o);
  }
  if (lane == 0) {
    l0 += blin[0];
    l1 += blin[1];
    float m = fmaxf(l0, l1);
    float lse = m + logf(expf(l0 - m) + expf(l1 - m));
    out[2 * q + 0] = l0 - lse;
    out[2 * q + 1] = l1 - lse;
  }
}

extern "C" void kernel_launch(void* const* d_in, const int* in_sizes, int n_in,
                              void* d_out, int out_size, void* d_ws, size_t ws_size,
                              hipStream_t stream) {
  const float* real = (const float*)d_in[0];
  const float* imag = (const float*)d_in[1];
  const int* ei     = (const int*)d_in[2];
  const int* qe     = (const int*)d_in[3];
  const float* ew   = (const float*)d_in[4];
  const float* W1   = (const float*)d_in[5];
  const float* b1   = (const float*)d_in[6];
  const float* W2   = (const float*)d_in[7];
  const float* b2   = (const float*)d_in[8];
  const float* Wlin = (const float*)d_in[9];
  const float* blin = (const float*)d_in[10];

  const int N = in_sizes[0] / 128;
  const int E = in_sizes[4];
  const int Q = in_sizes[3] / 2;
  const int* u = ei;
  const int* v = ei + E;

  float* ws = (float*)d_ws;
  size_t off = 0;
  auto alloc = [&](size_t n) { float* p = ws + off; off += n; return p; };
  const size_t N64 = (size_t)N * 64;
  const size_t N128 = (size_t)N * 128;
  const size_t N256 = (size_t)N * 256;

  float2* cf = (float2*)alloc((size_t)2 * E * 2);                 // 8B-aligned
  unsigned long long* dc = (unsigned long long*)alloc((size_t)2 * N);
  int* src  = (int*)alloc((size_t)2 * E);
  float* P1  = alloc(N128);
  float* P2  = alloc(N128);
  float* Z   = alloc(N256);
  float* HAr = alloc(N64);
  float* HAi = alloc(N64);
  float* HBr = alloc(N64);
  float* HBi = alloc(N64);
  int* rp   = (int*)alloc(N + 1);
  int* nxt  = (int*)alloc(N);
  int* bsum = (int*)alloc(64);
  (void)ws_size; (void)n_in; (void)out_size;

  const int eb = (E + 255) / 256;
  const int mb = (N + 31) / 32;
  const int NB = (N + 1023) / 1024;
  const int gb = (N + 3) / 4;
  const int epb = (E + mb - 1) / mb;  // edges per GEMM block (~320)

  // --- dispatch 1: layer-1 GEMM with deg-atomic prefix slices ---
  hipMemsetAsync(dc, 0, (size_t)N * 8, stream);
  k_gemm_deg<128><<<mb, 256, 0, stream>>>(
      u, v, ew, dc, E, epb, real, imag, W1, b1, P1, P2, HAr, HAi, N);
  // --- graph structure ---
  k_scan1<<<NB, 256, 0, stream>>>(dc, rp, bsum, N);
  k_scan3<<<(N + 256) / 256, 256, 0, stream>>>(rp, nxt, bsum, N, 2 * E);
  k_scatter<<<eb, 256, 0, stream>>>(u, v, ew, dc, nxt, src, cf, E);

  // --- layer 1 sparse ---
  k_gU<<<gb, 256, 0, stream>>>(src, cf, rp, P2, P1, Z, N);
  k_gC<<<gb, 256, 0, stream>>>(src, cf, rp, Z, HAr, HAi, N);

  // --- layer 2 ---
  k_gemmF<64><<<mb, 256, 0, stream>>>(HAr, HAi, W2, b2, P1, P2, HBr, HBi, N);
  k_gU<<<gb, 256, 0, stream>>>(src, cf, rp, P2, P1, Z, N);
  k_gC<<<gb, 256, 0, stream>>>(src, cf, rp, Z, HBr, HBi, N);

  // --- queries ---
  k_query<<<(Q + 3) / 4, 256, 0, stream>>>(qe, HBr, HBi, Wlin, blin, (float*)d_out, Q);
}